// Round 5
// baseline (665.505 us; speedup 1.0000x reference)
//
#include <hip/hip_runtime.h>
#include <math.h>

#define N_NODES 100000
#define N_EDGES 3200000
#define F_IN    128
#define NGRAPH  64

// ---- dst-binning: 256 buckets of BWIDTH nodes ----
#define NB      256
#define BWIDTH  391            // ceil(100000/256); 256*391 = 100096 >= N
#define BW16    (BWIDTH * 16)  // 6256 floats = 25 KB LDS accumulator
#define BIN_CAP 15000          // mean 12500, sigma ~111 -> +22 sigma
#define EPB     2048           // edges per bin_k block

typedef int   iv4 __attribute__((ext_vector_type(4)));
typedef float fv4 __attribute__((ext_vector_type(4)));

// Workspace layout (4-byte elements)
#define OFF_BINCUR 0                          // [256] int
#define OFF_DIS    256                        // [N] f32
#define OFF_BINNED 100352                     // [NB*BIN_CAP] int = 3,840,000
#define OFF_BUFA   (100352 + NB * BIN_CAP)    // [N*16] f32
#define OFF_BUFB   (OFF_BUFA + N_NODES * 16)  // [N*16] f32
// end = 100352 + 3840000 + 3200000 = 7,140,352 elems ~= 28.6 MB

// ---- pass A: bin edges by dst range; packed (dstLocal<<17 | src) ----
// Per-edge work is LDS-only; global traffic = coalesced ei read + segmented
// appends. Only NB global atomics per block (bucket cursors).
__global__ void bin_k(const int* __restrict__ ei, int* __restrict__ binCursor,
                      int* __restrict__ binned) {
    __shared__ int cntL[NB], cnt2[NB], gbase[NB];
    __shared__ int segBase[NB + 1];
    __shared__ int wsum[4];
    __shared__ int ldsOut[EPB];
    int tid = threadIdx.x;
    cntL[tid] = 0;
    cnt2[tid] = 0;
    __syncthreads();
    int myBase = blockIdx.x * EPB + tid * 8;
    bool act = (myBase < N_EDGES);   // tail divisible by 8 -> per-thread all-or-none
    int s[8], d[8];
    if (act) {
        const iv4* sp = (const iv4*)(ei + myBase);
        const iv4* dp = (const iv4*)(ei + N_EDGES + myBase);
        iv4 a = __builtin_nontemporal_load(sp);
        iv4 b2 = __builtin_nontemporal_load(sp + 1);
        iv4 c = __builtin_nontemporal_load(dp);
        iv4 e = __builtin_nontemporal_load(dp + 1);
        s[0]=a.x; s[1]=a.y; s[2]=a.z; s[3]=a.w; s[4]=b2.x; s[5]=b2.y; s[6]=b2.z; s[7]=b2.w;
        d[0]=c.x; d[1]=c.y; d[2]=c.z; d[3]=c.w; d[4]=e.x; d[5]=e.y; d[6]=e.z; d[7]=e.w;
#pragma unroll
        for (int k = 0; k < 8; ++k)
            atomicAdd(&cntL[(unsigned)d[k] / BWIDTH], 1);
    }
    __syncthreads();
    // 256-wide exclusive prefix over bucket counts (one thread per bucket)
    {
        int v = cntL[tid];
        int lane = tid & 63, wid = tid >> 6;
        int sc = v;
#pragma unroll
        for (int dd = 1; dd < 64; dd <<= 1) {
            int o = __shfl_up(sc, dd);
            if (lane >= dd) sc += o;
        }
        if (lane == 63) wsum[wid] = sc;
        __syncthreads();
        int woff = 0;
        for (int w = 0; w < wid; ++w) woff += wsum[w];
        segBase[tid] = woff + sc - v;            // exclusive
        if (tid == 255) segBase[NB] = woff + sc; // total
        gbase[tid] = atomicAdd(&binCursor[tid], v);
    }
    __syncthreads();
    if (act) {
#pragma unroll
        for (int k = 0; k < 8; ++k) {
            int b = (unsigned)d[k] / BWIDTH;
            int off = segBase[b] + atomicAdd(&cnt2[b], 1);
            ldsOut[off] = ((d[k] - b * BWIDTH) << 17) | s[k];
        }
    }
    __syncthreads();
    int total = segBase[NB];
    for (int i = tid; i < total; i += 256) {
        // largest b with segBase[b] <= i (8-step LDS binary search)
        int lo = 0, hi = NB;
        while (hi - lo > 1) { int m = (lo + hi) >> 1; if (segBase[m] <= i) lo = m; else hi = m; }
        binned[(size_t)lo * BIN_CAP + gbase[lo] + (i - segBase[lo])] = ldsOut[i];
    }
}

// ---- pass B: per-bucket degree histogram (LDS) -> dis, coalesced non-atomic ----
__global__ void hist_dis_k(const int* __restrict__ binCursor, const int* __restrict__ binned,
                           float* __restrict__ dis) {
    __shared__ int cnt[BWIDTH];
    int b = blockIdx.x, tid = threadIdx.x;
    for (int k = tid; k < BWIDTH; k += 256) cnt[k] = 0;
    __syncthreads();
    int n = binCursor[b];
    const int* bb = binned + (size_t)b * BIN_CAP;
    for (int i = tid; i < n; i += 256)
        atomicAdd(&cnt[bb[i] >> 17], 1);
    __syncthreads();
    int base = b * BWIDTH;
    int bw = min(BWIDTH, N_NODES - base);
    for (int k = tid; k < bw; k += 256)
        dis[base + k] = rsqrtf((float)cnt[k] + 1.0f);
}

// ---- h = x @ W1   (x: [N,128], W1: [128,16]) ----
__global__ void transform1_k(const float* __restrict__ x, const float* __restrict__ W,
                             float* __restrict__ out) {
    int i = blockIdx.x * blockDim.x + threadIdx.x;
    if (i >= N_NODES) return;
    const fv4* xr = (const fv4*)(x + (size_t)i * F_IN);
    float acc[16];
#pragma unroll
    for (int j = 0; j < 16; ++j) acc[j] = 0.f;
#pragma unroll 4
    for (int k4 = 0; k4 < F_IN / 4; ++k4) {
        fv4 xv = xr[k4];
#pragma unroll
        for (int kk = 0; kk < 4; ++kk) {
            int k = k4 * 4 + kk;
            float xk = xv[kk];
#pragma unroll
            for (int j = 0; j < 16; ++j)
                acc[j] = fmaf(xk, W[k * 16 + j], acc[j]);
        }
    }
    fv4* o = (fv4*)(out + (size_t)i * 16);
#pragma unroll
    for (int q = 0; q < 4; ++q) {
        fv4 t = { acc[q * 4], acc[q * 4 + 1], acc[q * 4 + 2], acc[q * 4 + 3] };
        o[q] = t;
    }
}

// ---- h = hin @ W2  (hin: [N,16], W2: [16,16]) ----
__global__ void transform2_k(const float* __restrict__ h, const float* __restrict__ W,
                             float* __restrict__ out) {
    int i = blockIdx.x * blockDim.x + threadIdx.x;
    if (i >= N_NODES) return;
    const fv4* hr = (const fv4*)(h + (size_t)i * 16);
    float hv[16];
#pragma unroll
    for (int q = 0; q < 4; ++q) {
        fv4 t = hr[q];
        hv[q * 4 + 0] = t.x; hv[q * 4 + 1] = t.y; hv[q * 4 + 2] = t.z; hv[q * 4 + 3] = t.w;
    }
    float acc[16];
#pragma unroll
    for (int j = 0; j < 16; ++j) acc[j] = 0.f;
#pragma unroll
    for (int k = 0; k < 16; ++k) {
#pragma unroll
        for (int j = 0; j < 16; ++j)
            acc[j] = fmaf(hv[k], W[k * 16 + j], acc[j]);
    }
    fv4* o = (fv4*)(out + (size_t)i * 16);
#pragma unroll
    for (int q = 0; q < 4; ++q) {
        fv4 t = { acc[q * 4], acc[q * 4 + 1], acc[q * 4 + 2], acc[q * 4 + 3] };
        o[q] = t;
    }
}

// ---- propagate, bucket-local: LDS f32 accumulator tile, zero global atomics.
// 16-lane group per edge: packed word + dis[s] broadcast, hin[s*16+j] = one
// coalesced 64B txn, ds_add_f32 into accum[dl][j] (2-way bank alias = free).
__global__ void __launch_bounds__(512)
prop_k(const float* __restrict__ hin, const float* __restrict__ dis,
       const int* __restrict__ binCursor, const int* __restrict__ binned,
       const float* __restrict__ bias, float* __restrict__ hout) {
    __shared__ float accum[BW16];
    int b = blockIdx.x, tid = threadIdx.x;
    for (int k = tid; k < BW16; k += 512) accum[k] = 0.f;
    __syncthreads();
    int n = binCursor[b];
    const int* bb = binned + (size_t)b * BIN_CAP;
    int grp = tid >> 4, j = tid & 15;   // 32 groups of 16 lanes
#pragma unroll 2
    for (int i = grp; i < n; i += 32) {
        int p = bb[i];
        int s = p & 0x1FFFF;
        int dl = p >> 17;
        atomicAdd(&accum[dl * 16 + j], dis[s] * hin[s * 16 + j]);
    }
    __syncthreads();
    int base = b * BWIDTH;
    int bw = min(BWIDTH, N_NODES - base);
    float bj = bias[j];
    for (int ln = grp; ln < bw; ln += 32) {
        int node = base + ln;
        float di = dis[node];
        float v = fmaf(di, accum[ln * 16 + j], fmaf(di * di, hin[node * 16 + j], bj));
        hout[node * 16 + j] = fmaxf(v, 0.f);
    }
}

// ---- pool per graph (batch sorted) + sigmoid(pooled @ fc_w + fc_b) ----
__global__ void pool_k(const float* __restrict__ h2, const int* __restrict__ batch,
                       const float* __restrict__ fcw, const float* __restrict__ fcb,
                       float* __restrict__ out) {
    __shared__ float partial[16][16];
    int g = blockIdx.x;
    int lane16 = threadIdx.x & 15, grp = threadIdx.x >> 4;
    int lo = 0, hi = N_NODES;
    while (lo < hi) { int m = (lo + hi) >> 1; if (batch[m] < g) lo = m + 1; else hi = m; }
    int start = lo;
    lo = start; hi = N_NODES;
    while (lo < hi) { int m = (lo + hi) >> 1; if (batch[m] < g + 1) lo = m + 1; else hi = m; }
    int end = lo;
    float acc = 0.f;
    for (int i = start + grp; i < end; i += 16) acc += h2[i * 16 + lane16];
    partial[grp][lane16] = acc;
    __syncthreads();
    if (threadIdx.x < 16) {
        float s = 0.f;
#pragma unroll
        for (int gg = 0; gg < 16; ++gg) s += partial[gg][threadIdx.x];
        partial[0][threadIdx.x] = s * fcw[threadIdx.x];
    }
    __syncthreads();
    if (threadIdx.x == 0) {
        float z = fcb[0];
#pragma unroll
        for (int j = 0; j < 16; ++j) z += partial[0][j];
        out[g] = 1.0f / (1.0f + expf(-z));
    }
}

extern "C" void kernel_launch(void* const* d_in, const int* in_sizes, int n_in,
                              void* d_out, int out_size, void* d_ws, size_t ws_size,
                              hipStream_t stream) {
    const float* x    = (const float*)d_in[0];
    const int*   ei   = (const int*)d_in[1];
    const int*   batch= (const int*)d_in[2];
    const float* W1   = (const float*)d_in[3];
    const float* b1   = (const float*)d_in[4];
    const float* W2   = (const float*)d_in[5];
    const float* b2   = (const float*)d_in[6];
    const float* fcw  = (const float*)d_in[7];
    const float* fcb  = (const float*)d_in[8];
    float* out = (float*)d_out;

    float* ws = (float*)d_ws;
    int*   binCur = (int*)(ws + OFF_BINCUR);
    float* dis    = ws + OFF_DIS;
    int*   binned = (int*)(ws + OFF_BINNED);
    float* bufA   = ws + OFF_BUFA;
    float* bufB   = ws + OFF_BUFB;

    (void)hipMemsetAsync(binCur, 0, NB * sizeof(int), stream);

    const int B = 256;
    int gN   = (N_NODES + B - 1) / B;        // 391
    int gBin = (N_EDGES + EPB - 1) / EPB;    // 1563

    bin_k<<<gBin, B, 0, stream>>>(ei, binCur, binned);
    hist_dis_k<<<NB, B, 0, stream>>>(binCur, binned, dis);

    transform1_k<<<gN, B, 0, stream>>>(x, W1, bufA);
    prop_k<<<NB, 512, 0, stream>>>(bufA, dis, binCur, binned, b1, bufB);
    transform2_k<<<gN, B, 0, stream>>>(bufB, W2, bufA);
    prop_k<<<NB, 512, 0, stream>>>(bufA, dis, binCur, binned, b2, bufB);
    pool_k<<<NGRAPH, B, 0, stream>>>(bufB, batch, fcw, fcb, out);
}

// Round 6
// 252.110 us; speedup vs baseline: 2.6397x; 2.6397x over previous
//
#include <hip/hip_runtime.h>
#include <math.h>

#define N_NODES 100000
#define N_EDGES 3200000
#define F_IN    128
#define NGRAPH  64

// ---- dst-binning: 256 buckets of BWIDTH nodes ----
#define NB      256
#define BWIDTH  391            // 256*391 = 100096 >= N
#define BIN_CAP 15000          // mean 12500, sigma ~111 -> +22 sigma
#define EPB     2048           // edges per bin_k block

typedef int   iv4 __attribute__((ext_vector_type(4)));
typedef float fv4 __attribute__((ext_vector_type(4)));

// Workspace layout (4-byte elements)
#define OFF_BINCUR 0            // [256] int
#define OFF_BBASE  256          // [256] int   exclusive scan of bin sizes
#define OFF_DIS    512          // [100352] f32 (N padded)
#define OFF_ROWR   100864       // [2*100096] int2 rowRange per node (8B aligned)
#define OFF_COL    301056       // [E] int     CSR col, dense
#define OFF_BINNED 3501056      // [NB*BIN_CAP] = 3,840,000 int (dead after sort_k)
#define OFF_BUFA   3501056      // [N*16] f32  (aliases binned)
#define OFF_BUFB   5101056      // [N*16] f32  (aliases binned tail)
// end = 3501056 + 3840000 = 7,341,056 elems ~= 29.4 MB

// ---- pass A: bin edges by dst range; packed (dstLocal<<17 | src) ----
__global__ void bin_k(const int* __restrict__ ei, int* __restrict__ binCursor,
                      int* __restrict__ binned) {
    __shared__ int cntL[NB], cnt2[NB], gbase[NB];
    __shared__ int segBase[NB + 1];
    __shared__ int wsum[4];
    __shared__ int ldsOut[EPB];
    int tid = threadIdx.x;
    cntL[tid] = 0;
    cnt2[tid] = 0;
    __syncthreads();
    int myBase = blockIdx.x * EPB + tid * 8;
    bool act = (myBase < N_EDGES);   // tail divisible by 8 -> per-thread all-or-none
    int s[8], d[8];
    if (act) {
        const iv4* sp = (const iv4*)(ei + myBase);
        const iv4* dp = (const iv4*)(ei + N_EDGES + myBase);
        iv4 a = __builtin_nontemporal_load(sp);
        iv4 b2 = __builtin_nontemporal_load(sp + 1);
        iv4 c = __builtin_nontemporal_load(dp);
        iv4 e = __builtin_nontemporal_load(dp + 1);
        s[0]=a.x; s[1]=a.y; s[2]=a.z; s[3]=a.w; s[4]=b2.x; s[5]=b2.y; s[6]=b2.z; s[7]=b2.w;
        d[0]=c.x; d[1]=c.y; d[2]=c.z; d[3]=c.w; d[4]=e.x; d[5]=e.y; d[6]=e.z; d[7]=e.w;
#pragma unroll
        for (int k = 0; k < 8; ++k)
            atomicAdd(&cntL[(unsigned)d[k] / BWIDTH], 1);
    }
    __syncthreads();
    {
        int v = cntL[tid];
        int lane = tid & 63, wid = tid >> 6;
        int sc = v;
#pragma unroll
        for (int dd = 1; dd < 64; dd <<= 1) {
            int o = __shfl_up(sc, dd);
            if (lane >= dd) sc += o;
        }
        if (lane == 63) wsum[wid] = sc;
        __syncthreads();
        int woff = 0;
        for (int w = 0; w < wid; ++w) woff += wsum[w];
        segBase[tid] = woff + sc - v;
        if (tid == 255) segBase[NB] = woff + sc;
        gbase[tid] = atomicAdd(&binCursor[tid], v);
    }
    __syncthreads();
    if (act) {
#pragma unroll
        for (int k = 0; k < 8; ++k) {
            int b = (unsigned)d[k] / BWIDTH;
            int off = segBase[b] + atomicAdd(&cnt2[b], 1);
            ldsOut[off] = ((d[k] - b * BWIDTH) << 17) | s[k];
        }
    }
    __syncthreads();
    int total = segBase[NB];
    for (int i = tid; i < total; i += 256) {
        int lo = 0, hi = NB;
        while (hi - lo > 1) { int m = (lo + hi) >> 1; if (segBase[m] <= i) lo = m; else hi = m; }
        binned[(size_t)lo * BIN_CAP + gbase[lo] + (i - segBase[lo])] = ldsOut[i];
    }
}

// ---- exclusive scan of 256 bucket sizes -> dense edge bases ----
__global__ void scan256_k(const int* __restrict__ binCur, int* __restrict__ bucketBase) {
    __shared__ int wsum[4];
    int tid = threadIdx.x;
    int v = binCur[tid];
    int lane = tid & 63, wid = tid >> 6;
    int sc = v;
#pragma unroll
    for (int d = 1; d < 64; d <<= 1) {
        int o = __shfl_up(sc, d);
        if (lane >= d) sc += o;
    }
    if (lane == 63) wsum[wid] = sc;
    __syncthreads();
    int woff = 0;
    for (int w = 0; w < wid; ++w) woff += wsum[w];
    bucketBase[tid] = woff + sc - v;
}

// ---- per-bucket counting sort: histogram -> dis + rowRange, scatter -> col.
// All cursors in LDS; col writes land in a 50KB window (L2-coalesced).
__global__ void __launch_bounds__(512)
sort_k(const int* __restrict__ binCursor, const int* __restrict__ bucketBase,
       const int* __restrict__ binned, float* __restrict__ dis,
       int2* __restrict__ rowRange, int* __restrict__ col) {
    __shared__ int cnt[BWIDTH];
    __shared__ int rowLoc[BWIDTH + 1];
    __shared__ int cur[BWIDTH];
    __shared__ int wsum[8];
    int b = blockIdx.x, tid = threadIdx.x;
    for (int k = tid; k < BWIDTH; k += 512) cnt[k] = 0;
    __syncthreads();
    int n = binCursor[b];
    const int* bb = binned + (size_t)b * BIN_CAP;
    for (int i = tid; i < n; i += 512)
        atomicAdd(&cnt[bb[i] >> 17], 1);
    __syncthreads();
    int base = b * BWIDTH;
    int bw = min(BWIDTH, N_NODES - base);
    for (int k = tid; k < bw; k += 512)
        dis[base + k] = rsqrtf((float)cnt[k] + 1.0f);
    // 512-wide exclusive scan over cnt[0..390]
    int a = (tid < BWIDTH) ? cnt[tid] : 0;
    int lane = tid & 63, wid = tid >> 6;
    int sc = a;
#pragma unroll
    for (int d = 1; d < 64; d <<= 1) {
        int o = __shfl_up(sc, d);
        if (lane >= d) sc += o;
    }
    if (lane == 63) wsum[wid] = sc;
    __syncthreads();
    int woff = 0;
    for (int w = 0; w < wid; ++w) woff += wsum[w];
    if (tid < BWIDTH) {
        int excl = woff + sc - a;
        rowLoc[tid] = excl;
        cur[tid] = excl;
    }
    if (tid == 0) rowLoc[BWIDTH] = n;
    __syncthreads();
    int eb = bucketBase[b];
    for (int k = tid; k < bw; k += 512) {
        int2 rr; rr.x = eb + rowLoc[k]; rr.y = eb + rowLoc[k + 1];
        rowRange[base + k] = rr;
    }
    for (int i = tid; i < n; i += 512) {
        int p = bb[i];
        int pos = atomicAdd(&cur[p >> 17], 1);
        col[eb + pos] = p & 0x1FFFF;
    }
}

// ---- hin' = dis[i] * (x @ W1) ----
__global__ void transform1_k(const float* __restrict__ x, const float* __restrict__ W,
                             const float* __restrict__ dis, float* __restrict__ out) {
    int i = blockIdx.x * blockDim.x + threadIdx.x;
    if (i >= N_NODES) return;
    const fv4* xr = (const fv4*)(x + (size_t)i * F_IN);
    float acc[16];
#pragma unroll
    for (int j = 0; j < 16; ++j) acc[j] = 0.f;
#pragma unroll 4
    for (int k4 = 0; k4 < F_IN / 4; ++k4) {
        fv4 xv = xr[k4];
#pragma unroll
        for (int kk = 0; kk < 4; ++kk) {
            int k = k4 * 4 + kk;
            float xk = xv[kk];
#pragma unroll
            for (int j = 0; j < 16; ++j)
                acc[j] = fmaf(xk, W[k * 16 + j], acc[j]);
        }
    }
    float di = dis[i];
    fv4* o = (fv4*)(out + (size_t)i * 16);
#pragma unroll
    for (int q = 0; q < 4; ++q) {
        fv4 t = { di * acc[q * 4], di * acc[q * 4 + 1], di * acc[q * 4 + 2], di * acc[q * 4 + 3] };
        o[q] = t;
    }
}

// ---- hin2' = dis[i] * (h @ W2) ----
__global__ void transform2_k(const float* __restrict__ h, const float* __restrict__ W,
                             const float* __restrict__ dis, float* __restrict__ out) {
    int i = blockIdx.x * blockDim.x + threadIdx.x;
    if (i >= N_NODES) return;
    const fv4* hr = (const fv4*)(h + (size_t)i * 16);
    float hv[16];
#pragma unroll
    for (int q = 0; q < 4; ++q) {
        fv4 t = hr[q];
        hv[q * 4 + 0] = t.x; hv[q * 4 + 1] = t.y; hv[q * 4 + 2] = t.z; hv[q * 4 + 3] = t.w;
    }
    float acc[16];
#pragma unroll
    for (int j = 0; j < 16; ++j) acc[j] = 0.f;
#pragma unroll
    for (int k = 0; k < 16; ++k) {
#pragma unroll
        for (int j = 0; j < 16; ++j)
            acc[j] = fmaf(hv[k], W[k * 16 + j], acc[j]);
    }
    float di = dis[i];
    fv4* o = (fv4*)(out + (size_t)i * 16);
#pragma unroll
    for (int q = 0; q < 4; ++q) {
        fv4 t = { di * acc[q * 4], di * acc[q * 4 + 1], di * acc[q * 4 + 2], di * acc[q * 4 + 3] };
        o[q] = t;
    }
}

// ---- node-parallel propagate: hout = relu(di*(sum hin'[src] + hin'[i]) + b)
// hin' already carries dis[src]; 16 lanes per node -> 64B coalesced gather;
// 2-way unroll keeps two independent gathers in flight. No atomics, no LDS.
__global__ void prop_k(const float* __restrict__ hin, const float* __restrict__ dis,
                       const int2* __restrict__ rowRange, const int* __restrict__ col,
                       const float* __restrict__ bias, float* __restrict__ hout) {
    int gid = blockIdx.x * blockDim.x + threadIdx.x;
    int node = gid >> 4;
    int j = gid & 15;
    if (node >= N_NODES) return;
    int2 rr = rowRange[node];
    float acc0 = 0.f, acc1 = 0.f;
    int e = rr.x;
    for (; e + 2 <= rr.y; e += 2) {
        int s0 = col[e];
        int s1 = col[e + 1];
        acc0 += hin[s0 * 16 + j];
        acc1 += hin[s1 * 16 + j];
    }
    if (e < rr.y) acc0 += hin[col[e] * 16 + j];
    float di = dis[node];
    float v = fmaf(di, acc0 + acc1 + hin[node * 16 + j], bias[j]);
    hout[node * 16 + j] = fmaxf(v, 0.f);
}

// ---- pool per graph (batch sorted) + sigmoid(pooled @ fc_w + fc_b) ----
__global__ void pool_k(const float* __restrict__ h2, const int* __restrict__ batch,
                       const float* __restrict__ fcw, const float* __restrict__ fcb,
                       float* __restrict__ out) {
    __shared__ float partial[16][16];
    int g = blockIdx.x;
    int lane16 = threadIdx.x & 15, grp = threadIdx.x >> 4;
    int lo = 0, hi = N_NODES;
    while (lo < hi) { int m = (lo + hi) >> 1; if (batch[m] < g) lo = m + 1; else hi = m; }
    int start = lo;
    lo = start; hi = N_NODES;
    while (lo < hi) { int m = (lo + hi) >> 1; if (batch[m] < g + 1) lo = m + 1; else hi = m; }
    int end = lo;
    float acc = 0.f;
    for (int i = start + grp; i < end; i += 16) acc += h2[i * 16 + lane16];
    partial[grp][lane16] = acc;
    __syncthreads();
    if (threadIdx.x < 16) {
        float s = 0.f;
#pragma unroll
        for (int gg = 0; gg < 16; ++gg) s += partial[gg][threadIdx.x];
        partial[0][threadIdx.x] = s * fcw[threadIdx.x];
    }
    __syncthreads();
    if (threadIdx.x == 0) {
        float z = fcb[0];
#pragma unroll
        for (int j = 0; j < 16; ++j) z += partial[0][j];
        out[g] = 1.0f / (1.0f + expf(-z));
    }
}

extern "C" void kernel_launch(void* const* d_in, const int* in_sizes, int n_in,
                              void* d_out, int out_size, void* d_ws, size_t ws_size,
                              hipStream_t stream) {
    const float* x    = (const float*)d_in[0];
    const int*   ei   = (const int*)d_in[1];
    const int*   batch= (const int*)d_in[2];
    const float* W1   = (const float*)d_in[3];
    const float* b1   = (const float*)d_in[4];
    const float* W2   = (const float*)d_in[5];
    const float* b2   = (const float*)d_in[6];
    const float* fcw  = (const float*)d_in[7];
    const float* fcb  = (const float*)d_in[8];
    float* out = (float*)d_out;

    float* ws = (float*)d_ws;
    int*   binCur   = (int*)(ws + OFF_BINCUR);
    int*   bucketBase = (int*)(ws + OFF_BBASE);
    float* dis      = ws + OFF_DIS;
    int2*  rowRange = (int2*)(ws + OFF_ROWR);
    int*   col      = (int*)(ws + OFF_COL);
    int*   binned   = (int*)(ws + OFF_BINNED);
    float* bufA     = ws + OFF_BUFA;   // aliases binned (dead after sort_k)
    float* bufB     = ws + OFF_BUFB;

    (void)hipMemsetAsync(binCur, 0, NB * sizeof(int), stream);

    const int B = 256;
    int gN   = (N_NODES + B - 1) / B;        // 391
    int gNH  = (N_NODES * 16 + B - 1) / B;   // 6250
    int gBin = (N_EDGES + EPB - 1) / EPB;    // 1563

    bin_k<<<gBin, B, 0, stream>>>(ei, binCur, binned);
    scan256_k<<<1, 256, 0, stream>>>(binCur, bucketBase);
    sort_k<<<NB, 512, 0, stream>>>(binCur, bucketBase, binned, dis, rowRange, col);

    transform1_k<<<gN, B, 0, stream>>>(x, W1, dis, bufA);
    prop_k<<<gNH, B, 0, stream>>>(bufA, dis, rowRange, col, b1, bufB);
    transform2_k<<<gN, B, 0, stream>>>(bufB, W2, dis, bufA);
    prop_k<<<gNH, B, 0, stream>>>(bufA, dis, rowRange, col, b2, bufB);
    pool_k<<<NGRAPH, B, 0, stream>>>(bufB, batch, fcw, fcb, out);
}

// Round 7
// 216.800 us; speedup vs baseline: 3.0697x; 1.1629x over previous
//
#include <hip/hip_runtime.h>
#include <math.h>

#define N_NODES 100000
#define N_EDGES 3200000
#define F_IN    128
#define NGRAPH  64

// ---- dst-binning: 256 buckets of BWIDTH nodes ----
#define NB      256
#define BWIDTH  391            // 256*391 = 100096 >= N
#define BIN_CAP 15000          // mean 12500, sigma ~111 -> +22 sigma
#define EPB     2048           // edges per bin_k block

typedef int   iv4 __attribute__((ext_vector_type(4)));
typedef float fv4 __attribute__((ext_vector_type(4)));
typedef float fv2 __attribute__((ext_vector_type(2)));

// Workspace layout (4-byte elements)
#define OFF_BINCUR 0            // [256] int
#define OFF_DIS    512          // [100352] f32 (N padded)
#define OFF_ROWR   100864       // [2*100096] int2 rowRange per node (8B aligned)
#define OFF_COL    301056       // [E] int     CSR col, dense
#define OFF_BINNED 3501056      // [NB*BIN_CAP] = 3,840,000 int (dead after sort_k)
#define OFF_BUFA   3501056      // [N*16] f32  (aliases binned)
#define OFF_BUFB   5101056      // [N*16] f32  (aliases binned tail)
// end = 3501056 + 3840000 = 7,341,056 elems ~= 29.4 MB

// ---- pass A: bin edges by dst range; packed (dstLocal<<17 | src) ----
__global__ void bin_k(const int* __restrict__ ei, int* __restrict__ binCursor,
                      int* __restrict__ binned) {
    __shared__ int cntL[NB], cnt2[NB], gbase[NB];
    __shared__ int segBase[NB + 1];
    __shared__ int wsum[4];
    __shared__ int ldsOut[EPB];
    int tid = threadIdx.x;
    cntL[tid] = 0;
    cnt2[tid] = 0;
    __syncthreads();
    int myBase = blockIdx.x * EPB + tid * 8;
    bool act = (myBase < N_EDGES);   // tail divisible by 8 -> per-thread all-or-none
    int s[8], d[8];
    if (act) {
        const iv4* sp = (const iv4*)(ei + myBase);
        const iv4* dp = (const iv4*)(ei + N_EDGES + myBase);
        iv4 a = __builtin_nontemporal_load(sp);
        iv4 b2 = __builtin_nontemporal_load(sp + 1);
        iv4 c = __builtin_nontemporal_load(dp);
        iv4 e = __builtin_nontemporal_load(dp + 1);
        s[0]=a.x; s[1]=a.y; s[2]=a.z; s[3]=a.w; s[4]=b2.x; s[5]=b2.y; s[6]=b2.z; s[7]=b2.w;
        d[0]=c.x; d[1]=c.y; d[2]=c.z; d[3]=c.w; d[4]=e.x; d[5]=e.y; d[6]=e.z; d[7]=e.w;
#pragma unroll
        for (int k = 0; k < 8; ++k)
            atomicAdd(&cntL[(unsigned)d[k] / BWIDTH], 1);
    }
    __syncthreads();
    {
        int v = cntL[tid];
        int lane = tid & 63, wid = tid >> 6;
        int sc = v;
#pragma unroll
        for (int dd = 1; dd < 64; dd <<= 1) {
            int o = __shfl_up(sc, dd);
            if (lane >= dd) sc += o;
        }
        if (lane == 63) wsum[wid] = sc;
        __syncthreads();
        int woff = 0;
        for (int w = 0; w < wid; ++w) woff += wsum[w];
        segBase[tid] = woff + sc - v;
        if (tid == 255) segBase[NB] = woff + sc;
        gbase[tid] = atomicAdd(&binCursor[tid], v);
    }
    __syncthreads();
    if (act) {
#pragma unroll
        for (int k = 0; k < 8; ++k) {
            int b = (unsigned)d[k] / BWIDTH;
            int off = segBase[b] + atomicAdd(&cnt2[b], 1);
            ldsOut[off] = ((d[k] - b * BWIDTH) << 17) | s[k];
        }
    }
    __syncthreads();
    int total = segBase[NB];
    for (int i = tid; i < total; i += 256) {
        int lo = 0, hi = NB;
        while (hi - lo > 1) { int m = (lo + hi) >> 1; if (segBase[m] <= i) lo = m; else hi = m; }
        binned[(size_t)lo * BIN_CAP + gbase[lo] + (i - segBase[lo])] = ldsOut[i];
    }
}

// ---- per-bucket counting sort: histogram -> dis + rowRange, scatter -> col.
// Bucket edge base computed in-block (reduction over binCursor) - no scan kernel.
__global__ void __launch_bounds__(512)
sort_k(const int* __restrict__ binCursor, const int* __restrict__ binned,
       float* __restrict__ dis, int2* __restrict__ rowRange, int* __restrict__ col) {
    __shared__ int cnt[BWIDTH];
    __shared__ int rowLoc[BWIDTH + 1];
    __shared__ int cur[BWIDTH];
    __shared__ int wsum[8];
    __shared__ int ebs;
    int b = blockIdx.x, tid = threadIdx.x;
    // eb = sum_{w<b} binCursor[w]
    if (tid < 256) cnt[tid] = (tid < b) ? binCursor[tid] : 0;
    __syncthreads();
#pragma unroll
    for (int st = 128; st > 0; st >>= 1) {
        if (tid < st) cnt[tid] += cnt[tid + st];
        __syncthreads();
    }
    if (tid == 0) ebs = cnt[0];
    __syncthreads();
    for (int k = tid; k < BWIDTH; k += 512) cnt[k] = 0;
    __syncthreads();
    int n = binCursor[b];
    const int* bb = binned + (size_t)b * BIN_CAP;
    for (int i = tid; i < n; i += 512)
        atomicAdd(&cnt[bb[i] >> 17], 1);
    __syncthreads();
    int base = b * BWIDTH;
    int bw = min(BWIDTH, N_NODES - base);
    for (int k = tid; k < bw; k += 512)
        dis[base + k] = rsqrtf((float)cnt[k] + 1.0f);
    // 512-wide exclusive scan over cnt[0..390]
    int a = (tid < BWIDTH) ? cnt[tid] : 0;
    int lane = tid & 63, wid = tid >> 6;
    int sc = a;
#pragma unroll
    for (int d = 1; d < 64; d <<= 1) {
        int o = __shfl_up(sc, d);
        if (lane >= d) sc += o;
    }
    if (lane == 63) wsum[wid] = sc;
    __syncthreads();
    int woff = 0;
    for (int w = 0; w < wid; ++w) woff += wsum[w];
    if (tid < BWIDTH) {
        int excl = woff + sc - a;
        rowLoc[tid] = excl;
        cur[tid] = excl;
    }
    if (tid == 0) rowLoc[BWIDTH] = n;
    __syncthreads();
    int eb = ebs;
    for (int k = tid; k < bw; k += 512) {
        int2 rr; rr.x = eb + rowLoc[k]; rr.y = eb + rowLoc[k + 1];
        rowRange[base + k] = rr;
    }
    for (int i = tid; i < n; i += 512) {
        int p = bb[i];
        int pos = atomicAdd(&cur[p >> 17], 1);
        col[eb + pos] = p & 0x1FFFF;
    }
}

// ---- hin' = dis[i] * (x @ W1) ----
__global__ void transform1_k(const float* __restrict__ x, const float* __restrict__ W,
                             const float* __restrict__ dis, float* __restrict__ out) {
    int i = blockIdx.x * blockDim.x + threadIdx.x;
    if (i >= N_NODES) return;
    const fv4* xr = (const fv4*)(x + (size_t)i * F_IN);
    float acc[16];
#pragma unroll
    for (int j = 0; j < 16; ++j) acc[j] = 0.f;
#pragma unroll 4
    for (int k4 = 0; k4 < F_IN / 4; ++k4) {
        fv4 xv = xr[k4];
#pragma unroll
        for (int kk = 0; kk < 4; ++kk) {
            int k = k4 * 4 + kk;
            float xk = xv[kk];
#pragma unroll
            for (int j = 0; j < 16; ++j)
                acc[j] = fmaf(xk, W[k * 16 + j], acc[j]);
        }
    }
    float di = dis[i];
    fv4* o = (fv4*)(out + (size_t)i * 16);
#pragma unroll
    for (int q = 0; q < 4; ++q) {
        fv4 t = { di * acc[q * 4], di * acc[q * 4 + 1], di * acc[q * 4 + 2], di * acc[q * 4 + 3] };
        o[q] = t;
    }
}

// ---- hin2' = dis[i] * (h @ W2) ----
__global__ void transform2_k(const float* __restrict__ h, const float* __restrict__ W,
                             const float* __restrict__ dis, float* __restrict__ out) {
    int i = blockIdx.x * blockDim.x + threadIdx.x;
    if (i >= N_NODES) return;
    const fv4* hr = (const fv4*)(h + (size_t)i * 16);
    float hv[16];
#pragma unroll
    for (int q = 0; q < 4; ++q) {
        fv4 t = hr[q];
        hv[q * 4 + 0] = t.x; hv[q * 4 + 1] = t.y; hv[q * 4 + 2] = t.z; hv[q * 4 + 3] = t.w;
    }
    float acc[16];
#pragma unroll
    for (int j = 0; j < 16; ++j) acc[j] = 0.f;
#pragma unroll
    for (int k = 0; k < 16; ++k) {
#pragma unroll
        for (int j = 0; j < 16; ++j)
            acc[j] = fmaf(hv[k], W[k * 16 + j], acc[j]);
    }
    float di = dis[i];
    fv4* o = (fv4*)(out + (size_t)i * 16);
#pragma unroll
    for (int q = 0; q < 4; ++q) {
        fv4 t = { di * acc[q * 4], di * acc[q * 4 + 1], di * acc[q * 4 + 2], di * acc[q * 4 + 3] };
        o[q] = t;
    }
}

// ---- node-parallel propagate: hout = relu(di*(sum hin'[src] + hin'[i]) + b)
// 8 lanes/node, float2/lane, unroll-4: 32 independent 64B gathers in flight
// per wave (4x round-6 MLP; that kernel was latency-bound at VALUBusy 19%).
__global__ void prop_k(const float* __restrict__ hin, const float* __restrict__ dis,
                       const int2* __restrict__ rowRange, const int* __restrict__ col,
                       const float* __restrict__ bias, float* __restrict__ hout) {
    int gid = blockIdx.x * blockDim.x + threadIdx.x;
    int node = gid >> 3;
    int j = gid & 7;
    if (node >= N_NODES) return;
    int2 rr = rowRange[node];
    const fv2* h2 = (const fv2*)hin;
    fv2 a0 = {0.f, 0.f}, a1 = {0.f, 0.f}, a2 = {0.f, 0.f}, a3 = {0.f, 0.f};
    int e = rr.x;
    for (; e + 4 <= rr.y; e += 4) {
        int s0 = col[e];
        int s1 = col[e + 1];
        int s2 = col[e + 2];
        int s3 = col[e + 3];
        a0 += h2[s0 * 8 + j];
        a1 += h2[s1 * 8 + j];
        a2 += h2[s2 * 8 + j];
        a3 += h2[s3 * 8 + j];
    }
    for (; e < rr.y; ++e) a0 += h2[col[e] * 8 + j];
    fv2 self = h2[node * 8 + j];
    float di = dis[node];
    fv2 bj = ((const fv2*)bias)[j];
    fv2 s = (a0 + a1) + (a2 + a3) + self;
    fv2 v;
    v.x = fmaxf(fmaf(di, s.x, bj.x), 0.f);
    v.y = fmaxf(fmaf(di, s.y, bj.y), 0.f);
    ((fv2*)hout)[node * 8 + j] = v;
}

// ---- pool per graph (batch sorted) + sigmoid(pooled @ fc_w + fc_b) ----
__global__ void pool_k(const float* __restrict__ h2, const int* __restrict__ batch,
                       const float* __restrict__ fcw, const float* __restrict__ fcb,
                       float* __restrict__ out) {
    __shared__ float partial[16][16];
    int g = blockIdx.x;
    int lane16 = threadIdx.x & 15, grp = threadIdx.x >> 4;
    int lo = 0, hi = N_NODES;
    while (lo < hi) { int m = (lo + hi) >> 1; if (batch[m] < g) lo = m + 1; else hi = m; }
    int start = lo;
    lo = start; hi = N_NODES;
    while (lo < hi) { int m = (lo + hi) >> 1; if (batch[m] < g + 1) lo = m + 1; else hi = m; }
    int end = lo;
    float acc = 0.f;
    for (int i = start + grp; i < end; i += 16) acc += h2[i * 16 + lane16];
    partial[grp][lane16] = acc;
    __syncthreads();
    if (threadIdx.x < 16) {
        float s = 0.f;
#pragma unroll
        for (int gg = 0; gg < 16; ++gg) s += partial[gg][threadIdx.x];
        partial[0][threadIdx.x] = s * fcw[threadIdx.x];
    }
    __syncthreads();
    if (threadIdx.x == 0) {
        float z = fcb[0];
#pragma unroll
        for (int j = 0; j < 16; ++j) z += partial[0][j];
        out[g] = 1.0f / (1.0f + expf(-z));
    }
}

extern "C" void kernel_launch(void* const* d_in, const int* in_sizes, int n_in,
                              void* d_out, int out_size, void* d_ws, size_t ws_size,
                              hipStream_t stream) {
    const float* x    = (const float*)d_in[0];
    const int*   ei   = (const int*)d_in[1];
    const int*   batch= (const int*)d_in[2];
    const float* W1   = (const float*)d_in[3];
    const float* b1   = (const float*)d_in[4];
    const float* W2   = (const float*)d_in[5];
    const float* b2   = (const float*)d_in[6];
    const float* fcw  = (const float*)d_in[7];
    const float* fcb  = (const float*)d_in[8];
    float* out = (float*)d_out;

    float* ws = (float*)d_ws;
    int*   binCur   = (int*)(ws + OFF_BINCUR);
    float* dis      = ws + OFF_DIS;
    int2*  rowRange = (int2*)(ws + OFF_ROWR);
    int*   col      = (int*)(ws + OFF_COL);
    int*   binned   = (int*)(ws + OFF_BINNED);
    float* bufA     = ws + OFF_BUFA;   // aliases binned (dead after sort_k)
    float* bufB     = ws + OFF_BUFB;

    (void)hipMemsetAsync(binCur, 0, NB * sizeof(int), stream);

    const int B = 256;
    int gN   = (N_NODES + B - 1) / B;        // 391
    int gNP  = (N_NODES * 8 + B - 1) / B;    // 3125
    int gBin = (N_EDGES + EPB - 1) / EPB;    // 1563

    bin_k<<<gBin, B, 0, stream>>>(ei, binCur, binned);
    sort_k<<<NB, 512, 0, stream>>>(binCur, binned, dis, rowRange, col);

    transform1_k<<<gN, B, 0, stream>>>(x, W1, dis, bufA);
    prop_k<<<gNP, B, 0, stream>>>(bufA, dis, rowRange, col, b1, bufB);
    transform2_k<<<gN, B, 0, stream>>>(bufB, W2, dis, bufA);
    prop_k<<<gNP, B, 0, stream>>>(bufA, dis, rowRange, col, b2, bufB);
    pool_k<<<NGRAPH, B, 0, stream>>>(bufB, batch, fcw, fcb, out);
}

// Round 8
// 202.083 us; speedup vs baseline: 3.2932x; 1.0728x over previous
//
#include <hip/hip_runtime.h>
#include <math.h>

#define N_NODES 100000
#define N_EDGES 3200000
#define F_IN    128
#define NGRAPH  64

// ---- dst-binning: 256 buckets of BWIDTH nodes ----
#define NB      256
#define BWIDTH  391            // 256*391 = 100096 >= N
#define BIN_CAP 15000          // mean 12500, sigma ~111 -> +22 sigma
#define EPB     4096           // edges per bin_k block (512 thr x 8)

typedef int   iv4 __attribute__((ext_vector_type(4)));
typedef float fv4 __attribute__((ext_vector_type(4)));
typedef float fv2 __attribute__((ext_vector_type(2)));

// Workspace layout (4-byte elements)
#define OFF_BINCUR 0            // [256] int
#define OFF_DIS    512          // [100352] f32 (N padded)
#define OFF_ROWR   100864       // [2*100096] int2 rowRange per node (8B aligned)
#define OFF_COL    301056       // [E] int     CSR col, dense
#define OFF_BINNED 3501056      // [NB*BIN_CAP] = 3,840,000 int (dead after sort_k)
#define OFF_BUFA   3501056      // [N*16] f32  (aliases binned)
#define OFF_BUFB   5101056      // [N*16] f32  (aliases binned tail)
// end = 3501056 + 3840000 = 7,341,056 elems ~= 29.4 MB

// ---- pass A: bin edges by dst range; packed (dstLocal<<17 | src) ----
// v2: no LDS repack / no binary search (round-7: 988K LDS bank conflicts,
// binary-search output loop dominated). Direct per-thread stores: each
// block's writes form ~16-int runs per bucket written in a tight window ->
// L2 merges them (block-local, unlike round-1's kernel-lifetime cursors).
__global__ void __launch_bounds__(512)
bin_k(const int* __restrict__ ei, int* __restrict__ binCursor,
      int* __restrict__ binned) {
    __shared__ int cntL[NB], cnt2[NB], gbase[NB];
    int tid = threadIdx.x;
    if (tid < NB) { cntL[tid] = 0; cnt2[tid] = 0; }
    __syncthreads();
    int myBase = blockIdx.x * EPB + tid * 8;
    bool act = (myBase < N_EDGES);   // tail multiple of 8 -> all-or-none per thread
    int s[8], d[8];
    if (act) {
        const iv4* sp = (const iv4*)(ei + myBase);
        const iv4* dp = (const iv4*)(ei + N_EDGES + myBase);
        iv4 a = __builtin_nontemporal_load(sp);
        iv4 b2 = __builtin_nontemporal_load(sp + 1);
        iv4 c = __builtin_nontemporal_load(dp);
        iv4 e = __builtin_nontemporal_load(dp + 1);
        s[0]=a.x; s[1]=a.y; s[2]=a.z; s[3]=a.w; s[4]=b2.x; s[5]=b2.y; s[6]=b2.z; s[7]=b2.w;
        d[0]=c.x; d[1]=c.y; d[2]=c.z; d[3]=c.w; d[4]=e.x; d[5]=e.y; d[6]=e.z; d[7]=e.w;
#pragma unroll
        for (int k = 0; k < 8; ++k)
            atomicAdd(&cntL[(unsigned)d[k] / BWIDTH], 1);
    }
    __syncthreads();
    if (tid < NB) gbase[tid] = atomicAdd(&binCursor[tid], cntL[tid]);
    __syncthreads();
    if (act) {
#pragma unroll
        for (int k = 0; k < 8; ++k) {
            int b = (unsigned)d[k] / BWIDTH;
            int off = atomicAdd(&cnt2[b], 1);
            binned[(size_t)b * BIN_CAP + gbase[b] + off] = ((d[k] - b * BWIDTH) << 17) | s[k];
        }
    }
}

// ---- per-bucket counting sort: histogram -> dis + rowRange, scatter -> col.
// Bucket edge base computed in-block (reduction over binCursor) - no scan kernel.
__global__ void __launch_bounds__(512)
sort_k(const int* __restrict__ binCursor, const int* __restrict__ binned,
       float* __restrict__ dis, int2* __restrict__ rowRange, int* __restrict__ col) {
    __shared__ int cnt[BWIDTH];
    __shared__ int rowLoc[BWIDTH + 1];
    __shared__ int cur[BWIDTH];
    __shared__ int wsum[8];
    __shared__ int ebs;
    int b = blockIdx.x, tid = threadIdx.x;
    // eb = sum_{w<b} binCursor[w]
    if (tid < 256) cnt[tid] = (tid < b) ? binCursor[tid] : 0;
    __syncthreads();
#pragma unroll
    for (int st = 128; st > 0; st >>= 1) {
        if (tid < st) cnt[tid] += cnt[tid + st];
        __syncthreads();
    }
    if (tid == 0) ebs = cnt[0];
    __syncthreads();
    for (int k = tid; k < BWIDTH; k += 512) cnt[k] = 0;
    __syncthreads();
    int n = binCursor[b];
    const int* bb = binned + (size_t)b * BIN_CAP;
    for (int i = tid; i < n; i += 512)
        atomicAdd(&cnt[bb[i] >> 17], 1);
    __syncthreads();
    int base = b * BWIDTH;
    int bw = min(BWIDTH, N_NODES - base);
    for (int k = tid; k < bw; k += 512)
        dis[base + k] = rsqrtf((float)cnt[k] + 1.0f);
    // 512-wide exclusive scan over cnt[0..390]
    int a = (tid < BWIDTH) ? cnt[tid] : 0;
    int lane = tid & 63, wid = tid >> 6;
    int sc = a;
#pragma unroll
    for (int d = 1; d < 64; d <<= 1) {
        int o = __shfl_up(sc, d);
        if (lane >= d) sc += o;
    }
    if (lane == 63) wsum[wid] = sc;
    __syncthreads();
    int woff = 0;
    for (int w = 0; w < wid; ++w) woff += wsum[w];
    if (tid < BWIDTH) {
        int excl = woff + sc - a;
        rowLoc[tid] = excl;
        cur[tid] = excl;
    }
    if (tid == 0) rowLoc[BWIDTH] = n;
    __syncthreads();
    int eb = ebs;
    for (int k = tid; k < bw; k += 512) {
        int2 rr; rr.x = eb + rowLoc[k]; rr.y = eb + rowLoc[k + 1];
        rowRange[base + k] = rr;
    }
    for (int i = tid; i < n; i += 512) {
        int p = bb[i];
        int pos = atomicAdd(&cur[p >> 17], 1);
        col[eb + pos] = p & 0x1FFFF;
    }
}

// ---- hin' = dis[i] * (x @ W1) ----
__global__ void transform1_k(const float* __restrict__ x, const float* __restrict__ W,
                             const float* __restrict__ dis, float* __restrict__ out) {
    int i = blockIdx.x * blockDim.x + threadIdx.x;
    if (i >= N_NODES) return;
    const fv4* xr = (const fv4*)(x + (size_t)i * F_IN);
    float acc[16];
#pragma unroll
    for (int j = 0; j < 16; ++j) acc[j] = 0.f;
#pragma unroll 4
    for (int k4 = 0; k4 < F_IN / 4; ++k4) {
        fv4 xv = xr[k4];
#pragma unroll
        for (int kk = 0; kk < 4; ++kk) {
            int k = k4 * 4 + kk;
            float xk = xv[kk];
#pragma unroll
            for (int j = 0; j < 16; ++j)
                acc[j] = fmaf(xk, W[k * 16 + j], acc[j]);
        }
    }
    float di = dis[i];
    fv4* o = (fv4*)(out + (size_t)i * 16);
#pragma unroll
    for (int q = 0; q < 4; ++q) {
        fv4 t = { di * acc[q * 4], di * acc[q * 4 + 1], di * acc[q * 4 + 2], di * acc[q * 4 + 3] };
        o[q] = t;
    }
}

// ---- hin2' = dis[i] * (h @ W2) ----
__global__ void transform2_k(const float* __restrict__ h, const float* __restrict__ W,
                             const float* __restrict__ dis, float* __restrict__ out) {
    int i = blockIdx.x * blockDim.x + threadIdx.x;
    if (i >= N_NODES) return;
    const fv4* hr = (const fv4*)(h + (size_t)i * 16);
    float hv[16];
#pragma unroll
    for (int q = 0; q < 4; ++q) {
        fv4 t = hr[q];
        hv[q * 4 + 0] = t.x; hv[q * 4 + 1] = t.y; hv[q * 4 + 2] = t.z; hv[q * 4 + 3] = t.w;
    }
    float acc[16];
#pragma unroll
    for (int j = 0; j < 16; ++j) acc[j] = 0.f;
#pragma unroll
    for (int k = 0; k < 16; ++k) {
#pragma unroll
        for (int j = 0; j < 16; ++j)
            acc[j] = fmaf(hv[k], W[k * 16 + j], acc[j]);
    }
    float di = dis[i];
    fv4* o = (fv4*)(out + (size_t)i * 16);
#pragma unroll
    for (int q = 0; q < 4; ++q) {
        fv4 t = { di * acc[q * 4], di * acc[q * 4 + 1], di * acc[q * 4 + 2], di * acc[q * 4 + 3] };
        o[q] = t;
    }
}

// ---- node-parallel propagate: hout = relu(di*(sum hin'[src] + hin'[i]) + b)
// 8 lanes/node, float2/lane, unroll-4: 32 independent 64B gathers in flight/wave.
__global__ void prop_k(const float* __restrict__ hin, const float* __restrict__ dis,
                       const int2* __restrict__ rowRange, const int* __restrict__ col,
                       const float* __restrict__ bias, float* __restrict__ hout) {
    int gid = blockIdx.x * blockDim.x + threadIdx.x;
    int node = gid >> 3;
    int j = gid & 7;
    if (node >= N_NODES) return;
    int2 rr = rowRange[node];
    const fv2* h2 = (const fv2*)hin;
    fv2 a0 = {0.f, 0.f}, a1 = {0.f, 0.f}, a2 = {0.f, 0.f}, a3 = {0.f, 0.f};
    int e = rr.x;
    for (; e + 4 <= rr.y; e += 4) {
        int s0 = col[e];
        int s1 = col[e + 1];
        int s2 = col[e + 2];
        int s3 = col[e + 3];
        a0 += h2[s0 * 8 + j];
        a1 += h2[s1 * 8 + j];
        a2 += h2[s2 * 8 + j];
        a3 += h2[s3 * 8 + j];
    }
    for (; e < rr.y; ++e) a0 += h2[col[e] * 8 + j];
    fv2 self = h2[node * 8 + j];
    float di = dis[node];
    fv2 bj = ((const fv2*)bias)[j];
    fv2 s = (a0 + a1) + (a2 + a3) + self;
    fv2 v;
    v.x = fmaxf(fmaf(di, s.x, bj.x), 0.f);
    v.y = fmaxf(fmaf(di, s.y, bj.y), 0.f);
    ((fv2*)hout)[node * 8 + j] = v;
}

// ---- pool per graph (batch sorted) + sigmoid(pooled @ fc_w + fc_b) ----
__global__ void pool_k(const float* __restrict__ h2, const int* __restrict__ batch,
                       const float* __restrict__ fcw, const float* __restrict__ fcb,
                       float* __restrict__ out) {
    __shared__ float partial[16][16];
    int g = blockIdx.x;
    int lane16 = threadIdx.x & 15, grp = threadIdx.x >> 4;
    int lo = 0, hi = N_NODES;
    while (lo < hi) { int m = (lo + hi) >> 1; if (batch[m] < g) lo = m + 1; else hi = m; }
    int start = lo;
    lo = start; hi = N_NODES;
    while (lo < hi) { int m = (lo + hi) >> 1; if (batch[m] < g + 1) lo = m + 1; else hi = m; }
    int end = lo;
    float acc = 0.f;
    for (int i = start + grp; i < end; i += 16) acc += h2[i * 16 + lane16];
    partial[grp][lane16] = acc;
    __syncthreads();
    if (threadIdx.x < 16) {
        float s = 0.f;
#pragma unroll
        for (int gg = 0; gg < 16; ++gg) s += partial[gg][threadIdx.x];
        partial[0][threadIdx.x] = s * fcw[threadIdx.x];
    }
    __syncthreads();
    if (threadIdx.x == 0) {
        float z = fcb[0];
#pragma unroll
        for (int j = 0; j < 16; ++j) z += partial[0][j];
        out[g] = 1.0f / (1.0f + expf(-z));
    }
}

extern "C" void kernel_launch(void* const* d_in, const int* in_sizes, int n_in,
                              void* d_out, int out_size, void* d_ws, size_t ws_size,
                              hipStream_t stream) {
    const float* x    = (const float*)d_in[0];
    const int*   ei   = (const int*)d_in[1];
    const int*   batch= (const int*)d_in[2];
    const float* W1   = (const float*)d_in[3];
    const float* b1   = (const float*)d_in[4];
    const float* W2   = (const float*)d_in[5];
    const float* b2   = (const float*)d_in[6];
    const float* fcw  = (const float*)d_in[7];
    const float* fcb  = (const float*)d_in[8];
    float* out = (float*)d_out;

    float* ws = (float*)d_ws;
    int*   binCur   = (int*)(ws + OFF_BINCUR);
    float* dis      = ws + OFF_DIS;
    int2*  rowRange = (int2*)(ws + OFF_ROWR);
    int*   col      = (int*)(ws + OFF_COL);
    int*   binned   = (int*)(ws + OFF_BINNED);
    float* bufA     = ws + OFF_BUFA;   // aliases binned (dead after sort_k)
    float* bufB     = ws + OFF_BUFB;

    (void)hipMemsetAsync(binCur, 0, NB * sizeof(int), stream);

    const int B = 256;
    int gN   = (N_NODES + B - 1) / B;        // 391
    int gNP  = (N_NODES * 8 + B - 1) / B;    // 3125
    int gBin = (N_EDGES + EPB - 1) / EPB;    // 782

    bin_k<<<gBin, 512, 0, stream>>>(ei, binCur, binned);
    sort_k<<<NB, 512, 0, stream>>>(binCur, binned, dis, rowRange, col);

    transform1_k<<<gN, B, 0, stream>>>(x, W1, dis, bufA);
    prop_k<<<gNP, B, 0, stream>>>(bufA, dis, rowRange, col, b1, bufB);
    transform2_k<<<gN, B, 0, stream>>>(bufB, W2, dis, bufA);
    prop_k<<<gNP, B, 0, stream>>>(bufA, dis, rowRange, col, b2, bufB);
    pool_k<<<NGRAPH, B, 0, stream>>>(bufB, batch, fcw, fcb, out);
}

// Round 9
// 176.545 us; speedup vs baseline: 3.7696x; 1.1447x over previous
//
#include <hip/hip_runtime.h>
#include <hip/hip_fp16.h>
#include <math.h>

#define N_NODES 100000
#define N_EDGES 3200000
#define F_IN    128
#define NGRAPH  64

// ---- dst-binning: 256 buckets of BWIDTH nodes ----
#define NB      256
#define BWIDTH  391            // 256*391 = 100096 >= N
#define BIN_CAP 15000          // mean 12500, sigma ~111 -> +22 sigma
#define EPB     4096           // edges per bin_k block (512 thr x 8)

typedef int   iv4 __attribute__((ext_vector_type(4)));
typedef float fv4 __attribute__((ext_vector_type(4)));
typedef float fv2 __attribute__((ext_vector_type(2)));

// Workspace layout (4-byte elements)
#define OFF_BINCUR 0            // [256] int
#define OFF_DIS    512          // [100352] f32 (N padded)
#define OFF_ROWR   100864       // [2*100096] int2 rowRange per node
#define OFF_COL    301056       // [E] int CSR col
#define OFF_BINNED 3501056      // [NB*BIN_CAP] int (dead after sort_k)
#define OFF_HINH   3501056      // [100096*16 halfs = 800768 words] fp16 hin' (aliases binned)
#define OFF_BUFB   4301824      // [N*16] f32
// end = 5,901,824 words ~= 23.6 MB (< prior 29.4 MB footprint)

// ---- pass A: bin edges by dst range; packed (dstLocal<<17 | src) ----
__global__ void __launch_bounds__(512)
bin_k(const int* __restrict__ ei, int* __restrict__ binCursor,
      int* __restrict__ binned) {
    __shared__ int cntL[NB], cnt2[NB], gbase[NB];
    int tid = threadIdx.x;
    if (tid < NB) { cntL[tid] = 0; cnt2[tid] = 0; }
    __syncthreads();
    int myBase = blockIdx.x * EPB + tid * 8;
    bool act = (myBase < N_EDGES);   // tail multiple of 8 -> all-or-none per thread
    int s[8], d[8];
    if (act) {
        const iv4* sp = (const iv4*)(ei + myBase);
        const iv4* dp = (const iv4*)(ei + N_EDGES + myBase);
        iv4 a = __builtin_nontemporal_load(sp);
        iv4 b2 = __builtin_nontemporal_load(sp + 1);
        iv4 c = __builtin_nontemporal_load(dp);
        iv4 e = __builtin_nontemporal_load(dp + 1);
        s[0]=a.x; s[1]=a.y; s[2]=a.z; s[3]=a.w; s[4]=b2.x; s[5]=b2.y; s[6]=b2.z; s[7]=b2.w;
        d[0]=c.x; d[1]=c.y; d[2]=c.z; d[3]=c.w; d[4]=e.x; d[5]=e.y; d[6]=e.z; d[7]=e.w;
#pragma unroll
        for (int k = 0; k < 8; ++k)
            atomicAdd(&cntL[(unsigned)d[k] / BWIDTH], 1);
    }
    __syncthreads();
    if (tid < NB) gbase[tid] = atomicAdd(&binCursor[tid], cntL[tid]);
    __syncthreads();
    if (act) {
#pragma unroll
        for (int k = 0; k < 8; ++k) {
            int b = (unsigned)d[k] / BWIDTH;
            int off = atomicAdd(&cnt2[b], 1);
            binned[(size_t)b * BIN_CAP + gbase[b] + off] = ((d[k] - b * BWIDTH) << 17) | s[k];
        }
    }
}

// ---- per-bucket counting sort: histogram -> dis + rowRange, scatter -> col ----
__global__ void __launch_bounds__(512)
sort_k(const int* __restrict__ binCursor, const int* __restrict__ binned,
       float* __restrict__ dis, int2* __restrict__ rowRange, int* __restrict__ col) {
    __shared__ int cnt[BWIDTH];
    __shared__ int rowLoc[BWIDTH + 1];
    __shared__ int cur[BWIDTH];
    __shared__ int wsum[8];
    __shared__ int ebs;
    int b = blockIdx.x, tid = threadIdx.x;
    if (tid < 256) cnt[tid] = (tid < b) ? binCursor[tid] : 0;
    __syncthreads();
#pragma unroll
    for (int st = 128; st > 0; st >>= 1) {
        if (tid < st) cnt[tid] += cnt[tid + st];
        __syncthreads();
    }
    if (tid == 0) ebs = cnt[0];
    __syncthreads();
    for (int k = tid; k < BWIDTH; k += 512) cnt[k] = 0;
    __syncthreads();
    int n = binCursor[b];
    const int* bb = binned + (size_t)b * BIN_CAP;
    for (int i = tid; i < n; i += 512)
        atomicAdd(&cnt[bb[i] >> 17], 1);
    __syncthreads();
    int base = b * BWIDTH;
    int bw = min(BWIDTH, N_NODES - base);
    for (int k = tid; k < bw; k += 512)
        dis[base + k] = rsqrtf((float)cnt[k] + 1.0f);
    int a = (tid < BWIDTH) ? cnt[tid] : 0;
    int lane = tid & 63, wid = tid >> 6;
    int sc = a;
#pragma unroll
    for (int d = 1; d < 64; d <<= 1) {
        int o = __shfl_up(sc, d);
        if (lane >= d) sc += o;
    }
    if (lane == 63) wsum[wid] = sc;
    __syncthreads();
    int woff = 0;
    for (int w = 0; w < wid; ++w) woff += wsum[w];
    if (tid < BWIDTH) {
        int excl = woff + sc - a;
        rowLoc[tid] = excl;
        cur[tid] = excl;
    }
    if (tid == 0) rowLoc[BWIDTH] = n;
    __syncthreads();
    int eb = ebs;
    for (int k = tid; k < bw; k += 512) {
        int2 rr; rr.x = eb + rowLoc[k]; rr.y = eb + rowLoc[k + 1];
        rowRange[base + k] = rr;
    }
    for (int i = tid; i < n; i += 512) {
        int p = bb[i];
        int pos = atomicAdd(&cur[p >> 17], 1);
        col[eb + pos] = p & 0x1FFFF;
    }
}

// ---- hin' = fp16( dis[i] * (x @ W1) ), packed 16 halfs/node (32B) ----
__global__ void transform1_k(const float* __restrict__ x, const float* __restrict__ W,
                             const float* __restrict__ dis, __half* __restrict__ outh) {
    int i = blockIdx.x * blockDim.x + threadIdx.x;
    if (i >= N_NODES) return;
    const fv4* xr = (const fv4*)(x + (size_t)i * F_IN);
    float acc[16];
#pragma unroll
    for (int j = 0; j < 16; ++j) acc[j] = 0.f;
#pragma unroll 4
    for (int k4 = 0; k4 < F_IN / 4; ++k4) {
        fv4 xv = xr[k4];
#pragma unroll
        for (int kk = 0; kk < 4; ++kk) {
            int k = k4 * 4 + kk;
            float xk = xv[kk];
#pragma unroll
            for (int j = 0; j < 16; ++j)
                acc[j] = fmaf(xk, W[k * 16 + j], acc[j]);
        }
    }
    float di = dis[i];
    __half2 t[8];
#pragma unroll
    for (int q = 0; q < 8; ++q)
        t[q] = __floats2half2_rn(di * acc[2 * q], di * acc[2 * q + 1]);
    iv4* o = (iv4*)(outh + (size_t)i * 16);
    o[0] = *(iv4*)&t[0];
    o[1] = *(iv4*)&t[4];
}

// ---- hin2' = fp16( dis[i] * (h @ W2) ) ----
__global__ void transform2_k(const float* __restrict__ h, const float* __restrict__ W,
                             const float* __restrict__ dis, __half* __restrict__ outh) {
    int i = blockIdx.x * blockDim.x + threadIdx.x;
    if (i >= N_NODES) return;
    const fv4* hr = (const fv4*)(h + (size_t)i * 16);
    float hv[16];
#pragma unroll
    for (int q = 0; q < 4; ++q) {
        fv4 t = hr[q];
        hv[q * 4 + 0] = t.x; hv[q * 4 + 1] = t.y; hv[q * 4 + 2] = t.z; hv[q * 4 + 3] = t.w;
    }
    float acc[16];
#pragma unroll
    for (int j = 0; j < 16; ++j) acc[j] = 0.f;
#pragma unroll
    for (int k = 0; k < 16; ++k) {
#pragma unroll
        for (int j = 0; j < 16; ++j)
            acc[j] = fmaf(hv[k], W[k * 16 + j], acc[j]);
    }
    float di = dis[i];
    __half2 t[8];
#pragma unroll
    for (int q = 0; q < 8; ++q)
        t[q] = __floats2half2_rn(di * acc[2 * q], di * acc[2 * q + 1]);
    iv4* o = (iv4*)(outh + (size_t)i * 16);
    o[0] = *(iv4*)&t[0];
    o[1] = *(iv4*)&t[4];
}

// ---- node-parallel propagate over fp16 hin' (3.2 MB -> per-XCD-L2 resident):
// 8 lanes/node, __half2/lane, unroll-4 (32 gathers in flight/wave), f32 accum,
// f32 output for the downstream transform/pool.
__global__ void prop_k(const __half* __restrict__ hinh, const float* __restrict__ dis,
                       const int2* __restrict__ rowRange, const int* __restrict__ col,
                       const float* __restrict__ bias, float* __restrict__ hout) {
    int gid = blockIdx.x * blockDim.x + threadIdx.x;
    int node = gid >> 3;
    int j = gid & 7;
    if (node >= N_NODES) return;
    int2 rr = rowRange[node];
    const __half2* hh = (const __half2*)hinh;
    float ax0 = 0.f, ay0 = 0.f, ax1 = 0.f, ay1 = 0.f;
    float ax2 = 0.f, ay2 = 0.f, ax3 = 0.f, ay3 = 0.f;
    int e = rr.x;
    for (; e + 4 <= rr.y; e += 4) {
        int s0 = col[e];
        int s1 = col[e + 1];
        int s2 = col[e + 2];
        int s3 = col[e + 3];
        float2 f0 = __half22float2(hh[s0 * 8 + j]);
        float2 f1 = __half22float2(hh[s1 * 8 + j]);
        float2 f2 = __half22float2(hh[s2 * 8 + j]);
        float2 f3 = __half22float2(hh[s3 * 8 + j]);
        ax0 += f0.x; ay0 += f0.y;
        ax1 += f1.x; ay1 += f1.y;
        ax2 += f2.x; ay2 += f2.y;
        ax3 += f3.x; ay3 += f3.y;
    }
    for (; e < rr.y; ++e) {
        float2 f = __half22float2(hh[col[e] * 8 + j]);
        ax0 += f.x; ay0 += f.y;
    }
    float2 self = __half22float2(hh[node * 8 + j]);
    float di = dis[node];
    fv2 bj = ((const fv2*)bias)[j];
    float sx = (ax0 + ax1) + (ax2 + ax3) + self.x;
    float sy = (ay0 + ay1) + (ay2 + ay3) + self.y;
    fv2 v;
    v.x = fmaxf(fmaf(di, sx, bj.x), 0.f);
    v.y = fmaxf(fmaf(di, sy, bj.y), 0.f);
    ((fv2*)hout)[node * 8 + j] = v;
}

// ---- pool per graph (batch sorted) + sigmoid(pooled @ fc_w + fc_b) ----
__global__ void pool_k(const float* __restrict__ h2, const int* __restrict__ batch,
                       const float* __restrict__ fcw, const float* __restrict__ fcb,
                       float* __restrict__ out) {
    __shared__ float partial[16][16];
    int g = blockIdx.x;
    int lane16 = threadIdx.x & 15, grp = threadIdx.x >> 4;
    int lo = 0, hi = N_NODES;
    while (lo < hi) { int m = (lo + hi) >> 1; if (batch[m] < g) lo = m + 1; else hi = m; }
    int start = lo;
    lo = start; hi = N_NODES;
    while (lo < hi) { int m = (lo + hi) >> 1; if (batch[m] < g + 1) lo = m + 1; else hi = m; }
    int end = lo;
    float acc = 0.f;
    for (int i = start + grp; i < end; i += 16) acc += h2[i * 16 + lane16];
    partial[grp][lane16] = acc;
    __syncthreads();
    if (threadIdx.x < 16) {
        float s = 0.f;
#pragma unroll
        for (int gg = 0; gg < 16; ++gg) s += partial[gg][threadIdx.x];
        partial[0][threadIdx.x] = s * fcw[threadIdx.x];
    }
    __syncthreads();
    if (threadIdx.x == 0) {
        float z = fcb[0];
#pragma unroll
        for (int j = 0; j < 16; ++j) z += partial[0][j];
        out[g] = 1.0f / (1.0f + expf(-z));
    }
}

extern "C" void kernel_launch(void* const* d_in, const int* in_sizes, int n_in,
                              void* d_out, int out_size, void* d_ws, size_t ws_size,
                              hipStream_t stream) {
    const float* x    = (const float*)d_in[0];
    const int*   ei   = (const int*)d_in[1];
    const int*   batch= (const int*)d_in[2];
    const float* W1   = (const float*)d_in[3];
    const float* b1   = (const float*)d_in[4];
    const float* W2   = (const float*)d_in[5];
    const float* b2   = (const float*)d_in[6];
    const float* fcw  = (const float*)d_in[7];
    const float* fcb  = (const float*)d_in[8];
    float* out = (float*)d_out;

    float* ws = (float*)d_ws;
    int*    binCur   = (int*)(ws + OFF_BINCUR);
    float*  dis      = ws + OFF_DIS;
    int2*   rowRange = (int2*)(ws + OFF_ROWR);
    int*    col      = (int*)(ws + OFF_COL);
    int*    binned   = (int*)(ws + OFF_BINNED);
    __half* hinH     = (__half*)(ws + OFF_HINH);   // aliases binned (dead after sort_k)
    float*  bufB     = ws + OFF_BUFB;

    (void)hipMemsetAsync(binCur, 0, NB * sizeof(int), stream);

    const int B = 256;
    int gN   = (N_NODES + B - 1) / B;        // 391
    int gNP  = (N_NODES * 8 + B - 1) / B;    // 3125
    int gBin = (N_EDGES + EPB - 1) / EPB;    // 782

    bin_k<<<gBin, 512, 0, stream>>>(ei, binCur, binned);
    sort_k<<<NB, 512, 0, stream>>>(binCur, binned, dis, rowRange, col);

    transform1_k<<<gN, B, 0, stream>>>(x, W1, dis, hinH);
    prop_k<<<gNP, B, 0, stream>>>(hinH, dis, rowRange, col, b1, bufB);
    transform2_k<<<gN, B, 0, stream>>>(bufB, W2, dis, hinH);
    prop_k<<<gNP, B, 0, stream>>>(hinH, dis, rowRange, col, b2, bufB);
    pool_k<<<NGRAPH, B, 0, stream>>>(bufB, batch, fcw, fcb, out);
}